// Round 13
// baseline (147.509 us; speedup 1.0000x reference)
//
#include <hip/hip_runtime.h>
#include <stdint.h>

// pairs_of_pairs: fused [concat -> conv1x1+relu x3]
// B=32, C=64, S=64, CC=128, OC=256. 2016 rows of 64 positions.
// R12: 1 row/block, 512 thr, 8 waves x 32o x 64pos, LDS 32KB -> target
// 2 blocks/CU co-resident (session evidence: 32KB -> 2 blocks, 64KB -> 1).
// Cross-block overlap hides the barrier-chain stalls that plateaued R5-R11
// at ~106us (1 block/CU, every pipe <=20% busy).
// Per kk: 2 A-loads (L2) + 4 B ds_reads -> 8 MFMA (ratios match R5's winner).
// X = 3 chunks [64pos][64ch] bf16 (24KB; rolled chunk aliased from chunk2 at
// shifted pos); h = [64pos][256ch] over 32KB; epilogue bounce = 2 passes of
// 128o x 64pos fp32 (32KB). Direct build (24 coalesced loads/thread, 1 bar).

typedef __attribute__((ext_vector_type(8))) __bf16 bf16x8;
typedef __attribute__((ext_vector_type(4))) float f32x4;
typedef __attribute__((ext_vector_type(4))) unsigned short u16x4;
typedef __attribute__((ext_vector_type(8))) unsigned short u16x8;

__device__ __forceinline__ unsigned short f2bf(float f) {
  unsigned int u = __builtin_bit_cast(unsigned int, f);
  u += 0x7FFFu + ((u >> 16) & 1u);
  return (unsigned short)(u >> 16);
}

// layer-0 chunks: chunk ck base = ck*4096 elems; [64 pos][64 ch] swizzled:
// 16B-slot = p*8 + ((c6>>3)^p)&7 -> ~2-way max.
__device__ __forceinline__ int xa(int ck, int p, int c6) {
  return ck * 4096 + (p * 8 + (((c6 >> 3) ^ p) & 7)) * 8 + (c6 & 7);
}
// h (layers 1-2 input): [64 pos][256 ch]: 16B-slot = p*32 + ((c>>3)^p)&31.
__device__ __forceinline__ int xh(int p, int c) {
  return (p * 32 + (((c >> 3) ^ p) & 31)) * 8 + (c & 7);
}

__global__ void wconv_kernel(const float* __restrict__ W1, const float* __restrict__ W2,
                             const float* __restrict__ W3, unsigned short* __restrict__ wb) {
  int i = (blockIdx.x * 256 + threadIdx.x) * 4;  // grid 64 -> 65536 per layer
  const float* Ws[3] = {W1, W2, W3};
#pragma unroll
  for (int L = 0; L < 3; ++L) {
    f32x4 a = *(const f32x4*)(Ws[L] + i);
    u16x4 p;
#pragma unroll
    for (int v = 0; v < 4; ++v) p[v] = f2bf(a[v]);
    *(u16x4*)(wb + L * 65536 + i) = p;
  }
}

__global__ __launch_bounds__(512, 2)
void fused_kernel(const float* __restrict__ x, const float* __restrict__ xc,
                  const unsigned short* __restrict__ wb,
                  const float* __restrict__ b1, const float* __restrict__ b2,
                  const float* __restrict__ b3, float* __restrict__ out) {
  __shared__ __align__(16) unsigned char lraw[32768];
  unsigned short* X = (unsigned short*)lraw;   // chunks 0-2 (24KB) / h (32KB)
  float* bounce = (float*)lraw;                // 32KB epilogue reuse

  const int r = blockIdx.x;       // 0..2015
  const int b = r / 63;
  const int dd = r % 63;
  const int d = dd + 1;
  const int tid = threadIdx.x;    // 0..511
  const int lane = tid & 63;
  const int g16 = lane >> 4;
  const int l16 = lane & 15;
  const int wv = tid >> 6;        // wave 0..7, owns o in [wv*32, wv*32+32)
  const int ow = wv * 32;

  // ---------------- build: direct global -> swizzled LDS, 1 barrier --------
  // 512 threads cover one 64pos x 64ch chunk per round: p = tid&63,
  // c-octet c0 = (tid>>6)*8. 8 coalesced f32 loads (lanes = consecutive pos,
  // 256B segments) -> bf16 pack -> 1 swizzled ds_write_b128.
  {
    const int p = tid & 63;
    const int c0 = (tid >> 6) << 3;   // 0,8,...,56
#pragma unroll
    for (int ck = 0; ck < 3; ++ck) {
      u16x8 v;
#pragma unroll
      for (int j = 0; j < 8; ++j) {
        float f = (ck < 2) ? xc[(((b * 128 + ck * 64 + c0 + j) * 63) + dd) * 64 + p]
                           : x[(b * 64 + c0 + j) * 64 + p];
        v[j] = f2bf(f);
      }
      *(u16x8*)&X[xa(ck, p, c0)] = v;
    }
  }
  __syncthreads();

  // ---------------- 3 fused conv1x1+relu layers ----------------
  const float* biases[3] = {b1, b2, b3};
  for (int layer = 0; layer < 3; ++layer) {
    const unsigned short* wl = wb + layer * 65536;
    const float* bias = biases[layer];
    const bool al3 = (layer == 0);   // layer-0 k>=192 aliases chunk2 shifted

    f32x4 acc[2][4] = {};            // [mf][nf], wave tile = 32 o x 64 pos

#pragma unroll
    for (int kk = 0; kk < 8; ++kk) {
      int kb = kk * 32 + g16 * 8;    // lane-group's 8-wide k-base
      bf16x8 afr[2];
#pragma unroll
      for (int mf = 0; mf < 2; ++mf)
        afr[mf] = __builtin_bit_cast(
            bf16x8, *(const u16x8*)(wl + (ow + mf * 16 + l16) * 256 + kb));
      bf16x8 bfr[4];
#pragma unroll
      for (int nf = 0; nf < 4; ++nf) {
        int p = nf * 16 + l16;       // position
        int addr;
        if (layer > 0)    addr = xh(p, kb);
        else if (kk < 2)  addr = xa(0, p, kb);
        else if (kk < 4)  addr = xa(1, p, kb - 64);
        else if (kk < 6)  addr = xa(2, p, kb - 128);
        else              addr = xa(2, (p - d) & 63, kb - 192);  // rolled x
        bfr[nf] = __builtin_bit_cast(bf16x8, *(const u16x8*)&X[addr]);
      }
#pragma unroll
      for (int mf = 0; mf < 2; ++mf)
#pragma unroll
        for (int nf = 0; nf < 4; ++nf)
          acc[mf][nf] = __builtin_amdgcn_mfma_f32_16x16x32_bf16(afr[mf], bfr[nf], acc[mf][nf], 0, 0, 0);
    }
    __syncthreads();  // all waves done reading X/h before overwrite

    if (layer < 2) {
      // bias + relu -> bf16 h (D frag: pos = l16 col, o = g16*4+v row)
#pragma unroll
      for (int mf = 0; mf < 2; ++mf) {
        int o0 = ow + mf * 16 + g16 * 4;
        f32x4 bv = *(const f32x4*)(bias + o0);
#pragma unroll
        for (int nf = 0; nf < 4; ++nf) {
          int p = nf * 16 + l16;
          u16x4 pk;
#pragma unroll
          for (int v = 0; v < 4; ++v)
            pk[v] = f2bf(fmaxf(acc[mf][nf][v] + bv[v], 0.f));
          *(u16x4*)&X[xh(p, o0)] = pk;
        }
      }
      __syncthreads();
    } else {
      // final: bias+relu -> fp32 bounce (LDS dead) -> f32x4 coalesced stores.
      // pass h covers o in [h*128, h*128+128) (32KB); waves wv>>2==h write.
#pragma unroll
      for (int h = 0; h < 2; ++h) {
        if (h) __syncthreads();      // pass-0 reads done before pass-1 writes
        if ((wv >> 2) == h) {
#pragma unroll
          for (int mf = 0; mf < 2; ++mf) {
            int olb = (wv & 3) * 32 + mf * 16 + g16 * 4;   // o - h*128
            f32x4 bv = *(const f32x4*)(bias + h * 128 + olb);
#pragma unroll
            for (int nf = 0; nf < 4; ++nf) {
              int p = nf * 16 + l16;
#pragma unroll
              for (int v = 0; v < 4; ++v) {
                int ol = olb + v;
                bounce[ol * 64 + (p ^ ((ol & 7) << 2))] =
                    fmaxf(acc[mf][nf][v] + bv[v], 0.f);
              }
            }
          }
        }
        __syncthreads();
        // read back along pos: 32KB = 2048 f32x4, 4 per thread
#pragma unroll
        for (int q = 0; q < 4; ++q) {
          int u = q * 512 + tid;     // 0..2047
          int oh = u >> 4;           // 0..127
          int p4 = (u & 15) << 2;
          f32x4 vv = *(const f32x4*)&bounce[oh * 64 + (p4 ^ ((oh & 7) << 2))];
          *(f32x4*)&out[(((b * 256 + h * 128 + oh) * 63) + dd) * 64 + p4] = vv;
        }
      }
    }
  }
}

extern "C" void kernel_launch(void* const* d_in, const int* in_sizes, int n_in,
                              void* d_out, int out_size, void* d_ws, size_t ws_size,
                              hipStream_t stream) {
  const float* x  = (const float*)d_in[0];
  const float* xc = (const float*)d_in[1];
  const float* W1 = (const float*)d_in[2];
  const float* b1 = (const float*)d_in[3];
  const float* W2 = (const float*)d_in[4];
  const float* b2 = (const float*)d_in[5];
  const float* W3 = (const float*)d_in[6];
  const float* b3 = (const float*)d_in[7];
  float* out = (float*)d_out;
  unsigned short* wb = (unsigned short*)d_ws;  // 3 x 256 x 256 bf16 = 384 KB

  wconv_kernel<<<64, 256, 0, stream>>>(W1, W2, W3, wb);
  fused_kernel<<<2016, 512, 0, stream>>>(x, xc, wb, b1, b2, b3, out);
}